// Round 7
// baseline (585.258 us; speedup 1.0000x reference)
//
#include <hip/hip_runtime.h>

#define LL 32
#define HH 64
#define SPB 8  // samples (waves) per block: 8 waves/CU = 2 waves/SIMD on 128 CUs

// Broadcast lane `lane`'s value of v to all lanes via v_readlane (SGPR result).
__device__ __forceinline__ float bcast_lane(float v, int lane) {
  return __builtin_bit_cast(float, __builtin_amdgcn_readlane(__builtin_bit_cast(int, v), lane));
}

// One DPP-shifted add step (bound_ctrl: out-of-range lanes contribute 0).
template <int CTRL>
__device__ __forceinline__ float dpp_add_step(float x) {
  int y = __builtin_amdgcn_update_dpp(0, __builtin_bit_cast(int, x), CTRL, 0xf, 0xf, true);
  return x + __builtin_bit_cast(float, y);
}

// Full 64-lane sum, broadcast wave-uniform (sum lands in lane 63 -> readlane).
__device__ __forceinline__ float wave_sum64(float x) {
  x = dpp_add_step<0x111>(x);  // row_shr:1
  x = dpp_add_step<0x112>(x);  // row_shr:2
  x = dpp_add_step<0x114>(x);  // row_shr:4
  x = dpp_add_step<0x118>(x);  // row_shr:8
  x = dpp_add_step<0x142>(x);  // row_bcast15
  x = dpp_add_step<0x143>(x);  // row_bcast31
  return __builtin_bit_cast(float, __builtin_amdgcn_readlane(__builtin_bit_cast(int, x), 63));
}

#define DECL_W(n) float w_##n = Wc[n * HH + lane];
#define MV4(i0, i1, i2, i3)                  \
  a0 = fmaf(bcast_lane(hv, i0), w_##i0, a0); \
  a1 = fmaf(bcast_lane(hv, i1), w_##i1, a1); \
  a2 = fmaf(bcast_lane(hv, i2), w_##i2, a2); \
  a3 = fmaf(bcast_lane(hv, i3), w_##i3, a3);

// Zero-instruction asm keeping all 64 Wc scalars + per-lane weights pinned in
// VGPRs across the loop (kept from R6; harmless, guards against remat).
#define PIN_ALL_W                                                              \
  asm volatile(""                                                              \
               : "+v"(w_0), "+v"(w_1), "+v"(w_2), "+v"(w_3), "+v"(w_4),       \
                 "+v"(w_5), "+v"(w_6), "+v"(w_7), "+v"(w_8), "+v"(w_9),       \
                 "+v"(w_10), "+v"(w_11), "+v"(w_12), "+v"(w_13), "+v"(w_14),  \
                 "+v"(w_15), "+v"(w_16), "+v"(w_17), "+v"(w_18), "+v"(w_19),  \
                 "+v"(w_20), "+v"(w_21), "+v"(w_22), "+v"(w_23), "+v"(w_24),  \
                 "+v"(w_25), "+v"(w_26), "+v"(w_27), "+v"(w_28), "+v"(w_29),  \
                 "+v"(w_30), "+v"(w_31), "+v"(w_32), "+v"(w_33), "+v"(w_34),  \
                 "+v"(w_35), "+v"(w_36), "+v"(w_37), "+v"(w_38), "+v"(w_39),  \
                 "+v"(w_40), "+v"(w_41), "+v"(w_42), "+v"(w_43), "+v"(w_44),  \
                 "+v"(w_45), "+v"(w_46), "+v"(w_47), "+v"(w_48), "+v"(w_49),  \
                 "+v"(w_50), "+v"(w_51), "+v"(w_52), "+v"(w_53), "+v"(w_54),  \
                 "+v"(w_55), "+v"(w_56), "+v"(w_57), "+v"(w_58), "+v"(w_59),  \
                 "+v"(w_60), "+v"(w_61), "+v"(w_62), "+v"(w_63), "+v"(win0),  \
                 "+v"(win1), "+v"(bcj), "+v"(dwout));

// 8 waves/block (one sample per wave): 128 blocks -> 1 block/CU on 128 CUs =
// 2 waves/SIMD. R6 showed 39% VALU idle at 1 wave/SIMD (dependent DPP/exp
// tails + readlane->SGPR hazards); a second resident wave fills those slots.
// Worst case it can't -> time unchanged (each wave's own latency is the floor).
__global__ __launch_bounds__(SPB * 64, 2) void rnn2d_kernel(
    const int* __restrict__ x, const float* __restrict__ Win,
    const float* __restrict__ Wc, const float* __restrict__ bc,
    const float* __restrict__ Wout, const float* __restrict__ bout,
    float* __restrict__ out) {
  const int lane = threadIdx.x & 63;
  const int wid = threadIdx.x >> 6;              // wave id within block = sample slot
  const int s = blockIdx.x * SPB + wid;          // sample index
  __shared__ float vrow_all[SPB * LL * HH];      // 64 KB: per-wave vertical carry
  float* vrow = vrow_all + wid * (LL * HH);

  DECL_W(0)  DECL_W(1)  DECL_W(2)  DECL_W(3)  DECL_W(4)  DECL_W(5)  DECL_W(6)  DECL_W(7)
  DECL_W(8)  DECL_W(9)  DECL_W(10) DECL_W(11) DECL_W(12) DECL_W(13) DECL_W(14) DECL_W(15)
  DECL_W(16) DECL_W(17) DECL_W(18) DECL_W(19) DECL_W(20) DECL_W(21) DECL_W(22) DECL_W(23)
  DECL_W(24) DECL_W(25) DECL_W(26) DECL_W(27) DECL_W(28) DECL_W(29) DECL_W(30) DECL_W(31)
  DECL_W(32) DECL_W(33) DECL_W(34) DECL_W(35) DECL_W(36) DECL_W(37) DECL_W(38) DECL_W(39)
  DECL_W(40) DECL_W(41) DECL_W(42) DECL_W(43) DECL_W(44) DECL_W(45) DECL_W(46) DECL_W(47)
  DECL_W(48) DECL_W(49) DECL_W(50) DECL_W(51) DECL_W(52) DECL_W(53) DECL_W(54) DECL_W(55)
  DECL_W(56) DECL_W(57) DECL_W(58) DECL_W(59) DECL_W(60) DECL_W(61) DECL_W(62) DECL_W(63)

  float win0 = Win[lane];                  // Win[0][j]
  float win1 = Win[HH + lane];             // Win[1][j]
  float bcj = bc[lane];
  float dwout = Wout[lane * 2 + 1] - Wout[lane * 2 + 0];  // Wout[j][1]-Wout[j][0]
  const float dbout = bout[1] - bout[0];   // wave-uniform scalar

  // Row 0 sees zero vertical hidden carry.
#pragma unroll
  for (int c0 = 0; c0 < LL; ++c0) vrow[c0 * HH + lane] = 0.f;

  const int* xb = x + s * (LL * LL);
  unsigned prevmask = 0u;                // previous row's spins (bit c = spin at col c)
  int spv = (lane < LL) ? xb[lane] : 0;  // prefetched row-0 spins
  float total_vec = 0.f;                 // per-lane partial of sum(logp)
  float dzbuf = 0.f;                     // lane k holds step-k signed logit gap (per row)

#pragma unroll 1
  for (int r = 0; r < LL; ++r) {
    const unsigned curmask =
        (unsigned)(__ballot(lane < LL && spv) & 0xffffffffull);
    if (r < LL - 1) spv = (lane < LL) ? xb[(r + 1) * LL + lane] : 0;

    const int odd = r & 1;
    const int d = odd ? -1 : 1;       // boustrophedon direction
    int c = odd ? (LL - 1) : 0;       // spatial column of scan step 0
    float hcur = 0.f;
    float vj = vrow[c * HH + lane];   // vertical carry for step 0

#pragma unroll 2
    for (int k = 0; k < LL; ++k) {
      PIN_ALL_W

      // Prefetch next step's vertical carry (that column not yet overwritten).
      const int cn = (c + d) & (LL - 1);
      const float vj_next = vrow[cn * HH + lane];

      const float hv = hcur + vj;  // (h + cV)[j], broadcast across lanes below

      // newH[j] = sum_i hv[i]*Wc[i][j]: 64 readlane broadcasts + 64 FMAs.
      float a0 = 0.f, a1 = 0.f, a2 = 0.f, a3 = 0.f;
      MV4(0, 1, 2, 3)     MV4(4, 5, 6, 7)     MV4(8, 9, 10, 11)   MV4(12, 13, 14, 15)
      MV4(16, 17, 18, 19) MV4(20, 21, 22, 23) MV4(24, 25, 26, 27) MV4(28, 29, 30, 31)
      MV4(32, 33, 34, 35) MV4(36, 37, 38, 39) MV4(40, 41, 42, 43) MV4(44, 45, 46, 47)
      MV4(48, 49, 50, 51) MV4(52, 53, 54, 55) MV4(56, 57, 58, 59) MV4(60, 61, 62, 63)

      // newR @ Win: one-hot selects (spins are wave-uniform bits of the masks).
      float winc = 0.f;
      if (k > 0) {
        const unsigned sh = (curmask >> ((c - d) & 31)) & 1u;
        winc += sh ? win1 : win0;
      }
      if (r > 0) {
        const unsigned sv = (prevmask >> c) & 1u;
        winc += sv ? win1 : win0;
      }

      const float pre = ((a0 + a1) + (a2 + a3)) + bcj + winc;
      const float hnew = pre > 0.f ? pre : (__expf(pre) - 1.f);  // elu

      vrow[c * HH + lane] = hnew;  // vertical carry for next row
      hcur = hnew;

      // Deferred logp: stash only the signed logit gap t_k = z_other - z_chosen
      // into lane k's slot; softplus happens once per row, vectorized. This cuts
      // the per-step dependent tail from ~110-150 cyc (DPP+exp+log chain at the
      // iteration bottom, un-overlappable under unroll 1) to ~10 instrs.
      const float dzv = wave_sum64(hnew * dwout) + dbout;  // z1 - z0, uniform
      const unsigned spin = (curmask >> c) & 1u;
      const float tv = spin ? -dzv : dzv;
      dzbuf = (lane == k) ? tv : dzbuf;

      vj = vj_next;
      c = cn;
    }
    prevmask = curmask;

    // Row epilogue: softplus for all 32 steps at once (lanes 0..31 hold t_k).
    //   logp_k = -softplus(t_k) = -(max(t,0) + log1p(exp(-|t|)))
    const float tt = dzbuf;
    float lpv = -(fmaxf(tt, 0.f) + __logf(1.f + __expf(-fabsf(tt))));
    lpv = (lpv == lpv) ? lpv : -35.0f;  // nan_to_num(nan=-35) per site
    total_vec += (lane < LL) ? lpv : 0.f;
  }

  const float grand = wave_sum64(total_vec);
  if (lane == 0) out[s] = 0.5f * grand;  // LOGP_FACTOR * sum
}

extern "C" void kernel_launch(void* const* d_in, const int* in_sizes, int n_in,
                              void* d_out, int out_size, void* d_ws, size_t ws_size,
                              hipStream_t stream) {
  const int* x = (const int*)d_in[0];
  const float* Win = (const float*)d_in[1];
  const float* Wc = (const float*)d_in[2];
  const float* bc = (const float*)d_in[3];
  const float* Wout = (const float*)d_in[4];
  const float* bout = (const float*)d_in[5];
  float* out = (float*)d_out;
  // 8 samples per block (one per wave) -> 2 waves/SIMD on the active CUs.
  rnn2d_kernel<<<dim3(out_size / SPB), dim3(SPB * 64), 0, stream>>>(
      x, Win, Wc, bc, Wout, bout, out);
}

// Round 8
// 420.888 us; speedup vs baseline: 1.3905x; 1.3905x over previous
//
#include <hip/hip_runtime.h>

#define LL 32
#define HH 64

// One DPP-shifted add step (bound_ctrl: out-of-range lanes contribute 0).
template <int CTRL>
__device__ __forceinline__ float dpp_add_step(float x) {
  int y = __builtin_amdgcn_update_dpp(0, __builtin_bit_cast(int, x), CTRL, 0xf, 0xf, true);
  return x + __builtin_bit_cast(float, y);
}

// Full 64-lane sum, broadcast wave-uniform (sum lands in lane 63 -> readlane).
__device__ __forceinline__ float wave_sum64(float x) {
  x = dpp_add_step<0x111>(x);  // row_shr:1
  x = dpp_add_step<0x112>(x);  // row_shr:2
  x = dpp_add_step<0x114>(x);  // row_shr:4
  x = dpp_add_step<0x118>(x);  // row_shr:8
  x = dpp_add_step<0x142>(x);  // row_bcast15
  x = dpp_add_step<0x143>(x);  // row_bcast31
  return __builtin_bit_cast(float, __builtin_amdgcn_readlane(__builtin_bit_cast(int, x), 63));
}

#define DECL_W(n) float w_##n = Wc[n * HH + lane];

// Matvec step for one float4 broadcast group g (hv[4g..4g+3], wave-uniform):
// a0..a3 are 4 independent accumulator chains; summation order identical to
// the R5-R7 readlane kernels (bit-identical results).
#define MV4(g, i0, i1, i2, i3)        \
  {                                   \
    const float4 hb = hv4[g];         \
    a0 = fmaf(hb.x, w_##i0, a0);      \
    a1 = fmaf(hb.y, w_##i1, a1);      \
    a2 = fmaf(hb.z, w_##i2, a2);      \
    a3 = fmaf(hb.w, w_##i3, a3);      \
  }

// Zero-instruction pin keeping the 64 Wc scalars + per-lane weights in VGPRs
// inside the loop (guards against invariant-load rematerialization).
#define PIN_ALL_W                                                              \
  asm volatile(""                                                              \
               : "+v"(w_0), "+v"(w_1), "+v"(w_2), "+v"(w_3), "+v"(w_4),       \
                 "+v"(w_5), "+v"(w_6), "+v"(w_7), "+v"(w_8), "+v"(w_9),       \
                 "+v"(w_10), "+v"(w_11), "+v"(w_12), "+v"(w_13), "+v"(w_14),  \
                 "+v"(w_15), "+v"(w_16), "+v"(w_17), "+v"(w_18), "+v"(w_19),  \
                 "+v"(w_20), "+v"(w_21), "+v"(w_22), "+v"(w_23), "+v"(w_24),  \
                 "+v"(w_25), "+v"(w_26), "+v"(w_27), "+v"(w_28), "+v"(w_29),  \
                 "+v"(w_30), "+v"(w_31), "+v"(w_32), "+v"(w_33), "+v"(w_34),  \
                 "+v"(w_35), "+v"(w_36), "+v"(w_37), "+v"(w_38), "+v"(w_39),  \
                 "+v"(w_40), "+v"(w_41), "+v"(w_42), "+v"(w_43), "+v"(w_44),  \
                 "+v"(w_45), "+v"(w_46), "+v"(w_47), "+v"(w_48), "+v"(w_49),  \
                 "+v"(w_50), "+v"(w_51), "+v"(w_52), "+v"(w_53), "+v"(w_54),  \
                 "+v"(w_55), "+v"(w_56), "+v"(w_57), "+v"(w_58), "+v"(w_59),  \
                 "+v"(w_60), "+v"(w_61), "+v"(w_62), "+v"(w_63), "+v"(win0),  \
                 "+v"(win1), "+v"(bcj), "+v"(dwout));

// One wave per sample, 1024 blocks on 1024 SIMDs (R7 lesson: with exactly 1024
// waves, clustering waves onto fewer SIMDs loses more than interleave gains —
// active-CU VALUBusy was already 82% at 2 waves/SIMD; per-SIMD count is fixed).
// Matvec broadcast via LDS uniform-address ds_read_b128 (same-address = HW
// broadcast, conflict-free): VALU does only the 64 FMAs; the 64 v_readlane
// SGPR-hazard ops of R2-R7 are gone.
__global__ __launch_bounds__(64, 1) void rnn2d_kernel(
    const int* __restrict__ x, const float* __restrict__ Win,
    const float* __restrict__ Wc, const float* __restrict__ bc,
    const float* __restrict__ Wout, const float* __restrict__ bout,
    float* __restrict__ out) {
  const int lane = threadIdx.x;
  const int b = blockIdx.x;
  __shared__ float vrow[LL * HH];   // vertical carry [column][hidden]
  __shared__ float hvbuf[2 * HH];   // double-buffered hv vector (step parity)

  DECL_W(0)  DECL_W(1)  DECL_W(2)  DECL_W(3)  DECL_W(4)  DECL_W(5)  DECL_W(6)  DECL_W(7)
  DECL_W(8)  DECL_W(9)  DECL_W(10) DECL_W(11) DECL_W(12) DECL_W(13) DECL_W(14) DECL_W(15)
  DECL_W(16) DECL_W(17) DECL_W(18) DECL_W(19) DECL_W(20) DECL_W(21) DECL_W(22) DECL_W(23)
  DECL_W(24) DECL_W(25) DECL_W(26) DECL_W(27) DECL_W(28) DECL_W(29) DECL_W(30) DECL_W(31)
  DECL_W(32) DECL_W(33) DECL_W(34) DECL_W(35) DECL_W(36) DECL_W(37) DECL_W(38) DECL_W(39)
  DECL_W(40) DECL_W(41) DECL_W(42) DECL_W(43) DECL_W(44) DECL_W(45) DECL_W(46) DECL_W(47)
  DECL_W(48) DECL_W(49) DECL_W(50) DECL_W(51) DECL_W(52) DECL_W(53) DECL_W(54) DECL_W(55)
  DECL_W(56) DECL_W(57) DECL_W(58) DECL_W(59) DECL_W(60) DECL_W(61) DECL_W(62) DECL_W(63)

  float win0 = Win[lane];                  // Win[0][j]
  float win1 = Win[HH + lane];             // Win[1][j]
  float bcj = bc[lane];
  float dwout = Wout[lane * 2 + 1] - Wout[lane * 2 + 0];  // Wout[j][1]-Wout[j][0]
  const float dbout = bout[1] - bout[0];   // wave-uniform scalar

  // Row 0 sees zero vertical hidden carry; step-0 hv is also zero.
#pragma unroll
  for (int c0 = 0; c0 < LL; ++c0) vrow[c0 * HH + lane] = 0.f;
  hvbuf[lane] = 0.f;  // buffer 0 holds hv for the very first step

  const int* xb = x + b * (LL * LL);
  unsigned prevmask = 0u;                // previous row's spins (bit c = spin at col c)
  int spv = (lane < LL) ? xb[lane] : 0;  // prefetched row-0 spins
  float total_vec = 0.f;                 // per-lane partial of sum(logp)
  float dzbuf = 0.f;                     // lane k holds step-k signed logit gap

#pragma unroll 1
  for (int r = 0; r < LL; ++r) {
    const unsigned curmask =
        (unsigned)(__ballot(lane < LL && spv) & 0xffffffffull);
    if (r < LL - 1) spv = (lane < LL) ? xb[(r + 1) * LL + lane] : 0;

    const int odd = r & 1;
    const int d = odd ? -1 : 1;       // boustrophedon direction
    int c = odd ? (LL - 1) : 0;       // spatial column of scan step 0

#pragma unroll 2
    for (int k = 0; k < LL; ++k) {
      PIN_ALL_W

      // Wave-uniform broadcast source for this step's hv (parity buffer).
      const float4* hv4 = (const float4*)(hvbuf + ((k & 1) ? HH : 0));

      // Prefetch next step's vertical carry (lane-strided, conflict-free;
      // that column is not yet overwritten this row).
      const int cn = (c + d) & (LL - 1);
      const float vjn = vrow[cn * HH + lane];

      // newH[j] = sum_i hv[i]*Wc[i][j]: 16 broadcast b128 reads + 64 FMAs.
      float a0 = 0.f, a1 = 0.f, a2 = 0.f, a3 = 0.f;
      MV4(0, 0, 1, 2, 3)      MV4(1, 4, 5, 6, 7)      MV4(2, 8, 9, 10, 11)
      MV4(3, 12, 13, 14, 15)  MV4(4, 16, 17, 18, 19)  MV4(5, 20, 21, 22, 23)
      MV4(6, 24, 25, 26, 27)  MV4(7, 28, 29, 30, 31)  MV4(8, 32, 33, 34, 35)
      MV4(9, 36, 37, 38, 39)  MV4(10, 40, 41, 42, 43) MV4(11, 44, 45, 46, 47)
      MV4(12, 48, 49, 50, 51) MV4(13, 52, 53, 54, 55) MV4(14, 56, 57, 58, 59)
      MV4(15, 60, 61, 62, 63)

      // newR @ Win: one-hot selects (spins are wave-uniform bits of the masks).
      float winc = 0.f;
      if (k > 0) {
        const unsigned sh = (curmask >> ((c - d) & 31)) & 1u;
        winc += sh ? win1 : win0;
      }
      if (r > 0) {
        const unsigned sv = (prevmask >> c) & 1u;
        winc += sv ? win1 : win0;
      }

      const float pre = ((a0 + a1) + (a2 + a3)) + bcj + winc;
      const float hnew = pre > 0.f ? pre : (__expf(pre) - 1.f);  // elu

      vrow[c * HH + lane] = hnew;  // vertical carry for next row

      // Store next step's hv IMMEDIATELY (hides the LDS write->read round trip
      // behind the logp tail below). At k==31 the next step is the next row's
      // step 0: hcur resets to 0 and it re-enters at this same column, whose
      // vertical carry is exactly hnew -> hv_next = hnew + 0. One uniform rule.
      const float hvn = hnew + ((k < LL - 1) ? vjn : 0.f);
      hvbuf[((k & 1) ? 0 : HH) + lane] = hvn;

      // Deferred logp: stash signed logit gap t_k in lane k; softplus once/row.
      const float dzv = wave_sum64(hnew * dwout) + dbout;  // z1 - z0, uniform
      const unsigned spin = (curmask >> c) & 1u;
      const float tv = spin ? -dzv : dzv;
      dzbuf = (lane == k) ? tv : dzbuf;

      c = cn;
    }
    prevmask = curmask;

    // Row epilogue: softplus for all 32 steps at once (lanes 0..31 hold t_k).
    //   logp_k = -softplus(t_k) = -(max(t,0) + log1p(exp(-|t|)))
    const float tt = dzbuf;
    float lpv = -(fmaxf(tt, 0.f) + __logf(1.f + __expf(-fabsf(tt))));
    lpv = (lpv == lpv) ? lpv : -35.0f;  // nan_to_num(nan=-35) per site
    total_vec += (lane < LL) ? lpv : 0.f;
  }

  const float grand = wave_sum64(total_vec);
  if (lane == 0) out[b] = 0.5f * grand;  // LOGP_FACTOR * sum
}

extern "C" void kernel_launch(void* const* d_in, const int* in_sizes, int n_in,
                              void* d_out, int out_size, void* d_ws, size_t ws_size,
                              hipStream_t stream) {
  const int* x = (const int*)d_in[0];
  const float* Win = (const float*)d_in[1];
  const float* Wc = (const float*)d_in[2];
  const float* bc = (const float*)d_in[3];
  const float* Wout = (const float*)d_in[4];
  const float* bout = (const float*)d_in[5];
  float* out = (float*)d_out;
  // One 64-thread block (one wave) per batch sample.
  rnn2d_kernel<<<dim3(out_size), dim3(64), 0, stream>>>(x, Win, Wc, bc, Wout, bout, out);
}